// Round 1
// baseline (1075.150 us; speedup 1.0000x reference)
//
#include <hip/hip_runtime.h>
#include <math.h>

#define N_PTS 8192
#define D_FEAT 768

// ---------------- FPS: one block per (scale,batch) ----------------
// scale 0: g C=256, 1: c C=128, 2: d C=64. idx layout: g[0,512) c[512,768) d[768,896)
__global__ __launch_bounds__(1024) void fps_kernel(const float* __restrict__ coords,
                                                   int* __restrict__ idx_all) {
#pragma clang fp contract(off)
    const int bid = blockIdx.x;       // 0..5
    const int scale = bid >> 1;
    const int b = bid & 1;
    const int C = (scale == 0) ? 256 : (scale == 1) ? 128 : 64;
    int* idx_out = idx_all + ((scale == 0) ? 0 : (scale == 1) ? 512 : 768) + b * C;

    const int t = threadIdx.x;
    const float* cb = coords + (size_t)b * N_PTS * 3;

    float px[8], py[8], pz[8], dist[8];
#pragma unroll
    for (int k = 0; k < 8; k++) {
        int p = t + k * 1024;
        px[k] = cb[p * 3 + 0];
        py[k] = cb[p * 3 + 1];
        pz[k] = cb[p * 3 + 2];
        dist[k] = INFINITY;
    }
    __shared__ float red_d[16];
    __shared__ int   red_i[16];
    __shared__ float lastx, lasty, lastz;
    if (t == 0) { idx_out[0] = 0; lastx = cb[0]; lasty = cb[1]; lastz = cb[2]; }
    __syncthreads();

    const int lane = t & 63, wid = t >> 6;
    for (int i = 1; i < C; i++) {
        float lx = lastx, ly = lasty, lz = lastz;
        float bd = -1.0f; int bi = 0x7fffffff;
#pragma unroll
        for (int k = 0; k < 8; k++) {
            float dx = px[k] - lx, dy = py[k] - ly, dz = pz[k] - lz;
            float d2 = dx * dx + dy * dy + dz * dz;   // contract off: matches numpy op order
            float d = sqrtf(d2);                       // correctly rounded, matches np.sqrt
            float nd = fminf(dist[k], d);
            dist[k] = nd;
            if (nd > bd) { bd = nd; bi = t + k * 1024; }  // ascending index -> first-max
        }
#pragma unroll
        for (int off = 32; off >= 1; off >>= 1) {
            float od = __shfl_down(bd, off, 64);
            int   oi = __shfl_down(bi, off, 64);
            if (od > bd || (od == bd && oi < bi)) { bd = od; bi = oi; }
        }
        if (lane == 0) { red_d[wid] = bd; red_i[wid] = bi; }
        __syncthreads();
        float fbd = red_d[0]; int fbi = red_i[0];
#pragma unroll
        for (int w = 1; w < 16; w++) {
            float od = red_d[w]; int oi = red_i[w];
            if (od > fbd || (od == fbd && oi < fbi)) { fbd = od; fbi = oi; }
        }
        if (t == 0) idx_out[i] = fbi;
        if (t == (fbi & 1023)) {
            int k = fbi >> 10;
            dist[k] = 0.0f;
            lastx = px[k]; lasty = py[k]; lastz = pz[k];
        }
        __syncthreads();
    }
}

// ---------------- z stats + safety for global & component ----------------
__global__ __launch_bounds__(1024) void safety_gc_kernel(const float* __restrict__ coords,
                                                         const int* __restrict__ idx_all,
                                                         float* __restrict__ safety_all) {
    const int b = blockIdx.x;
    const int t = threadIdx.x;
    const float* cb = coords + (size_t)b * N_PTS * 3;
    float s1 = 0.f, s2 = 0.f;
#pragma unroll
    for (int k = 0; k < 8; k++) {
        float z = cb[(t + k * 1024) * 3 + 2];
        s1 += z; s2 += z * z;
    }
    __shared__ float r1[16], r2[16];
#pragma unroll
    for (int off = 32; off >= 1; off >>= 1) {
        s1 += __shfl_down(s1, off, 64);
        s2 += __shfl_down(s2, off, 64);
    }
    int lane = t & 63, wid = t >> 6;
    if (lane == 0) { r1[wid] = s1; r2[wid] = s2; }
    __syncthreads();
    float S1 = 0.f, S2 = 0.f;
#pragma unroll
    for (int w = 0; w < 16; w++) { S1 += r1[w]; S2 += r2[w]; }
    float mean = S1 / 8192.0f;
    float var1 = (S2 - S1 * S1 / 8192.0f) / 8191.0f;           // ddof=1
    float sc = 1.0f + expf(-var1 / 0.1f) * 0.9f;               // component safety (≈1.0)
    for (int u = t; u < 256; u += 1024) {
        int p = idx_all[b * 256 + u];
        float z = cb[p * 3 + 2];
        float s = 1.0f + (1.0f / (1.0f + expf(-((z - mean) / 5.0f)))) * 0.95f;
        safety_all[b * 256 + u] = s;
    }
    for (int u = t; u < 128; u += 1024) safety_all[512 + b * 128 + u] = sc;
}

// ---------------- detail density safety: one block per sampled center ----------------
__global__ __launch_bounds__(256) void density_kernel(const float* __restrict__ coords,
                                                      const int* __restrict__ idx_all,
                                                      float* __restrict__ safety_all) {
#pragma clang fp contract(off)
    const int ci = blockIdx.x & 63;
    const int b  = blockIdx.x >> 6;
    const int t  = threadIdx.x;
    const float* cb = coords + (size_t)b * N_PTS * 3;
    const int p = idx_all[768 + b * 64 + ci];
    const float cx = cb[p * 3], cy = cb[p * 3 + 1], cz = cb[p * 3 + 2];
    const float cc = cx * cx + cy * cy + cz * cz;
    int cnt = 0;
    for (int k = 0; k < 32; k++) {
        int q = t + k * 256;
        float x = cb[q * 3], y = cb[q * 3 + 1], z = cb[q * 3 + 2];
        float pp = x * x + y * y + z * z;
        float dot = cx * x + cy * y + cz * z;
        float d2 = (cc + pp) - 2.0f * dot;   // same formula/order as reference _sqdist
        if (d2 < 0.25f) cnt++;               // clamp(max,0) irrelevant for <0.25
    }
#pragma unroll
    for (int off = 32; off >= 1; off >>= 1) cnt += __shfl_down(cnt, off, 64);
    __shared__ int rc[4];
    int lane = t & 63, wid = t >> 6;
    if (lane == 0) rc[wid] = cnt;
    __syncthreads();
    if (t == 0) {
        int tot = rc[0] + rc[1] + rc[2] + rc[3];
        safety_all[768 + b * 64 + ci] = 1.0f + ((float)tot / 8192.0f) * 0.95f;
    }
}

// ---------------- per-scale score MLP: 8 centers per block ----------------
// grid: g blocks [0,64), c [64,96), d [96,112)
__global__ __launch_bounds__(256) void score_kernel(
    const float* __restrict__ feat,
    const float* __restrict__ gW1, const float* __restrict__ gb1,
    const float* __restrict__ gW2, const float* __restrict__ gb2,
    const float* __restrict__ cW1, const float* __restrict__ cb1,
    const float* __restrict__ cW2, const float* __restrict__ cb2,
    const float* __restrict__ dW1, const float* __restrict__ db1,
    const float* __restrict__ dW2, const float* __restrict__ db2,
    const int* __restrict__ idx_all, const float* __restrict__ safety_all,
    float* __restrict__ final_all) {
    int bid = blockIdx.x;
    int b, c0, C, S, off;
    const float *W1, *b1, *W2, *b2;
    if (bid < 64)      { C = 256; S = 16; W1 = gW1; b1 = gb1; W2 = gW2; b2 = gb2; b = bid >> 5; c0 = (bid & 31) * 8; off = 0; }
    else if (bid < 96) { int r = bid - 64; C = 128; S = 16; W1 = cW1; b1 = cb1; W2 = cW2; b2 = cb2; b = r >> 4; c0 = (r & 15) * 8; off = 512; }
    else               { int r = bid - 96; C = 64;  S = 8;  W1 = dW1; b1 = db1; W2 = dW2; b2 = db2; b = r >> 3; c0 = (r & 7) * 8; off = 768; }

    __shared__ float xt[8 * 772];    // 8 cfeat rows, stride 772 (bank-safe, 16B aligned)
    __shared__ float h1s[8 * 260];   // hidden, stride 260
    __shared__ float ps[8 * 16];
    __shared__ int pid[8];
    const int t = threadIdx.x;
    if (t < 8) pid[t] = idx_all[off + b * C + c0 + t];
    __syncthreads();

    for (int r = 0; r < 8; r++) {
        const float* src = feat + ((size_t)b * N_PTS + pid[r]) * D_FEAT;
        for (int c = t; c < 768; c += 256) xt[r * 772 + c] = src[c];
    }
    __syncthreads();

    // phase B: h1 = relu(x @ W1^T + b1). thread tile: 4 j x 2 r
    {
        int rp = t & 3;          // rows 2*rp, 2*rp+1
        int jg = t >> 2;         // 64 groups of 4 outputs
        int r0 = rp * 2;
        if (jg * 4 < C) {
            float4 acc0[4], acc1[4];
#pragma unroll
            for (int a = 0; a < 4; a++) { acc0[a] = make_float4(0, 0, 0, 0); acc1[a] = make_float4(0, 0, 0, 0); }
            for (int k = 0; k < 768; k += 4) {
                float4 x0 = *(const float4*)&xt[r0 * 772 + k];
                float4 x1 = *(const float4*)&xt[(r0 + 1) * 772 + k];
#pragma unroll
                for (int a = 0; a < 4; a++) {
                    int j = jg * 4 + a;
                    float4 w = *(const float4*)&W1[(size_t)j * 768 + k];
                    acc0[a].x = fmaf(w.x, x0.x, acc0[a].x); acc0[a].y = fmaf(w.y, x0.y, acc0[a].y);
                    acc0[a].z = fmaf(w.z, x0.z, acc0[a].z); acc0[a].w = fmaf(w.w, x0.w, acc0[a].w);
                    acc1[a].x = fmaf(w.x, x1.x, acc1[a].x); acc1[a].y = fmaf(w.y, x1.y, acc1[a].y);
                    acc1[a].z = fmaf(w.z, x1.z, acc1[a].z); acc1[a].w = fmaf(w.w, x1.w, acc1[a].w);
                }
            }
#pragma unroll
            for (int a = 0; a < 4; a++) {
                int j = jg * 4 + a;
                float bb = b1[j];
                float v0 = (acc0[a].x + acc0[a].y) + (acc0[a].z + acc0[a].w) + bb;
                float v1 = (acc1[a].x + acc1[a].y) + (acc1[a].z + acc1[a].w) + bb;
                h1s[r0 * 260 + j]       = fmaxf(v0, 0.f);
                h1s[(r0 + 1) * 260 + j] = fmaxf(v1, 0.f);
            }
        }
    }
    __syncthreads();

    // phase C: probs = sigmoid(h1 @ W2^T + b2)
    if (t < 8 * S) {
        int r = t / S, s = t % S;
        float4 a = make_float4(0, 0, 0, 0);
        for (int k = 0; k < C; k += 4) {
            float4 w = *(const float4*)&W2[s * C + k];
            float4 h = *(const float4*)&h1s[r * 260 + k];
            a.x = fmaf(w.x, h.x, a.x); a.y = fmaf(w.y, h.y, a.y);
            a.z = fmaf(w.z, h.z, a.z); a.w = fmaf(w.w, h.w, a.w);
        }
        float logit = (a.x + a.y) + (a.z + a.w) + b2[s];
        ps[r * 16 + s] = 1.0f / (1.0f + expf(-logit));
    }
    __syncthreads();
    if (t < 8) {
        float m = 0.f;
        for (int s = 0; s < S; s++) m += ps[t * 16 + s];
        m /= (float)S;
        final_all[off + b * C + c0 + t] = m * safety_all[off + b * C + c0 + t];
    }
}

// ---------------- top-k per (scale,batch): single wave ----------------
__global__ __launch_bounds__(64) void topk_kernel(const int* __restrict__ idx_all,
                                                  const float* __restrict__ final_all,
                                                  int* __restrict__ tok_pidx) {
    int bid = blockIdx.x;  // 0..5
    int scale = bid >> 1, b = bid & 1;
    int C = (scale == 0) ? 256 : (scale == 1) ? 128 : 64;
    int S = (scale == 2) ? 8 : 16;
    int off = (scale == 0) ? 0 : (scale == 1) ? 512 : 768;
    int base = (scale == 0) ? 0 : (scale == 1) ? 16 : 32;
    int lane = threadIdx.x;
    float v[4];
#pragma unroll
    for (int j = 0; j < 4; j++) {
        int i = lane + j * 64;
        v[j] = (i < C) ? final_all[off + b * C + i] : -INFINITY;
    }
    for (int s = 0; s < S; s++) {
        float bd = -INFINITY; int bi = 0x7fffffff;
#pragma unroll
        for (int j = 0; j < 4; j++) {
            int i = lane + j * 64;
            if (i < C && v[j] > bd) { bd = v[j]; bi = i; }
        }
        for (int m = 1; m < 64; m <<= 1) {
            float od = __shfl_xor(bd, m, 64);
            int   oi = __shfl_xor(bi, m, 64);
            if (od > bd || (od == bd && oi < bi)) { bd = od; bi = oi; }
        }
        if (lane == (bi & 63)) v[bi >> 6] = -INFINITY;
        if (lane == 0) tok_pidx[b * 40 + base + s] = idx_all[off + b * C + bi];
    }
}

// ---------------- final MLP + LayerNorm: 2 tokens per block ----------------
__global__ __launch_bounds__(256) void final_kernel(
    const float* __restrict__ feat, const int* __restrict__ tok_pidx,
    const float* __restrict__ pW1, const float* __restrict__ pb1,
    const float* __restrict__ pW2, const float* __restrict__ pb2,
    const float* __restrict__ lng, const float* __restrict__ lnb,
    float* __restrict__ out) {
    int bid = blockIdx.x;               // 40 blocks
    int b = bid / 20, pr = bid % 20;
    int t = threadIdx.x;
    __shared__ float xt[2 * 772];       // token rows, then reused for h2
    __shared__ float h1s[2 * 388];
    __shared__ float red[16];

    for (int r = 0; r < 2; r++) {
        int tok = pr * 2 + r;
        int p = tok_pidx[b * 40 + tok];
        const float* src = feat + ((size_t)b * N_PTS + p) * D_FEAT;
        for (int c = t; c < 768; c += 256) xt[r * 772 + c] = src[c];
    }
    __syncthreads();

    // h1 = relu(x @ pW1^T + pb1): 384 x 2 units
    for (int u = t; u < 768; u += 256) {
        int j = u >> 1, r = u & 1;
        float4 a = make_float4(0, 0, 0, 0);
        for (int k = 0; k < 768; k += 4) {
            float4 w = *(const float4*)&pW1[(size_t)j * 768 + k];
            float4 x = *(const float4*)&xt[r * 772 + k];
            a.x = fmaf(w.x, x.x, a.x); a.y = fmaf(w.y, x.y, a.y);
            a.z = fmaf(w.z, x.z, a.z); a.w = fmaf(w.w, x.w, a.w);
        }
        float v = (a.x + a.y) + (a.z + a.w) + pb1[j];
        h1s[r * 388 + j] = fmaxf(v, 0.f);
    }
    __syncthreads();

    // h2 = h1 @ pW2^T + pb2: 768 x 2 units, store into xt (reuse)
    for (int u = t; u < 1536; u += 256) {
        int o = u >> 1, r = u & 1;
        float4 a = make_float4(0, 0, 0, 0);
        for (int k = 0; k < 384; k += 4) {
            float4 w = *(const float4*)&pW2[(size_t)o * 384 + k];
            float4 h = *(const float4*)&h1s[r * 388 + k];
            a.x = fmaf(w.x, h.x, a.x); a.y = fmaf(w.y, h.y, a.y);
            a.z = fmaf(w.z, h.z, a.z); a.w = fmaf(w.w, h.w, a.w);
        }
        xt[r * 772 + o] = (a.x + a.y) + (a.z + a.w) + pb2[o];
    }
    __syncthreads();

    // LayerNorm per row
    for (int r = 0; r < 2; r++) {
        float s1 = 0.f, s2 = 0.f;
        for (int o = t; o < 768; o += 256) { float v = xt[r * 772 + o]; s1 += v; s2 += v * v; }
#pragma unroll
        for (int off2 = 32; off2 >= 1; off2 >>= 1) {
            s1 += __shfl_down(s1, off2, 64);
            s2 += __shfl_down(s2, off2, 64);
        }
        int lane = t & 63, wid = t >> 6;
        if (lane == 0) { red[wid * 2] = s1; red[wid * 2 + 1] = s2; }
        __syncthreads();
        float S1 = red[0] + red[2] + red[4] + red[6];
        float S2 = red[1] + red[3] + red[5] + red[7];
        float mu = S1 / 768.0f;
        float var = S2 / 768.0f - mu * mu;
        float inv = rsqrtf(var + 1e-5f);
        int tok = pr * 2 + r;
        float* dst = out + ((size_t)b * 40 + tok) * 768;
        for (int o = t; o < 768; o += 256) {
            float v = xt[r * 772 + o];
            dst[o] = (v - mu) * inv * lng[o] + lnb[o];
        }
        __syncthreads();
    }
}

extern "C" void kernel_launch(void* const* d_in, const int* in_sizes, int n_in,
                              void* d_out, int out_size, void* d_ws, size_t ws_size,
                              hipStream_t stream) {
    const float* feat   = (const float*)d_in[0];
    const float* coords = (const float*)d_in[1];
    const float* gW1 = (const float*)d_in[2],  *gb1 = (const float*)d_in[3];
    const float* gW2 = (const float*)d_in[4],  *gb2 = (const float*)d_in[5];
    const float* cW1 = (const float*)d_in[6],  *cb1 = (const float*)d_in[7];
    const float* cW2 = (const float*)d_in[8],  *cb2 = (const float*)d_in[9];
    const float* dW1 = (const float*)d_in[10], *db1 = (const float*)d_in[11];
    const float* dW2 = (const float*)d_in[12], *db2 = (const float*)d_in[13];
    const float* pW1 = (const float*)d_in[14], *pb1 = (const float*)d_in[15];
    const float* pW2 = (const float*)d_in[16], *pb2 = (const float*)d_in[17];
    const float* lng = (const float*)d_in[18], *lnb = (const float*)d_in[19];
    float* out = (float*)d_out;

    // workspace: 896 idx (int) | 896 safety (f32) | 896 final (f32) | 80 tok_pidx (int)
    int*   idx_all    = (int*)d_ws;
    float* safety_all = (float*)d_ws + 896;
    float* final_all  = (float*)d_ws + 1792;
    int*   tok_pidx   = (int*)d_ws + 2688;

    fps_kernel<<<6, 1024, 0, stream>>>(coords, idx_all);
    safety_gc_kernel<<<2, 1024, 0, stream>>>(coords, idx_all, safety_all);
    density_kernel<<<128, 256, 0, stream>>>(coords, idx_all, safety_all);
    score_kernel<<<112, 256, 0, stream>>>(feat, gW1, gb1, gW2, gb2, cW1, cb1, cW2, cb2,
                                          dW1, db1, dW2, db2, idx_all, safety_all, final_all);
    topk_kernel<<<6, 64, 0, stream>>>(idx_all, final_all, tok_pidx);
    final_kernel<<<40, 256, 0, stream>>>(feat, tok_pidx, pW1, pb1, pW2, pb2, lng, lnb, out);
}

// Round 2
// 958.839 us; speedup vs baseline: 1.1213x; 1.1213x over previous
//
#include <hip/hip_runtime.h>
#include <math.h>

#define N_PTS 8192
#define D_FEAT 768

// ---------------- FPS: one block per batch ----------------
// FPS sequence is prefix-consistent in num_samples, so one 256-step run per
// batch serves all three scales. idx layout: g[0,512) c[512,768) d[768,896)
__global__ __launch_bounds__(1024) void fps_kernel(const float* __restrict__ coords,
                                                   int* __restrict__ idx_all) {
#pragma clang fp contract(off)
    const int b = blockIdx.x;         // 0..1
    const int t = threadIdx.x;
    const float* cb = coords + (size_t)b * N_PTS * 3;
    int* og = idx_all + b * 256;
    int* oc = idx_all + 512 + b * 128;
    int* od = idx_all + 768 + b * 64;

    // per-thread state in REGISTERS ONLY (no dynamic indexing anywhere!)
    float px[8], py[8], pz[8], dist[8], d2ub[8];
#pragma unroll
    for (int k = 0; k < 8; k++) {
        int p = t + k * 1024;
        px[k] = cb[p * 3 + 0];
        py[k] = cb[p * 3 + 1];
        pz[k] = cb[p * 3 + 2];
        dist[k] = INFINITY;
        d2ub[k] = INFINITY;
    }
    __shared__ float red_d[2][16];
    __shared__ int   red_i[2][16];
    if (t == 0) { og[0] = 0; oc[0] = 0; od[0] = 0; }
    __syncthreads();

    const int lane = t & 63, wid = t >> 6;
    int lastIdx = 0;
    for (int i = 1; i < 256; i++) {
        // broadcast read of current center coords (uniform address -> 1 txn, L1/L2 hit)
        const float lx = cb[lastIdx * 3 + 0];
        const float ly = cb[lastIdx * 3 + 1];
        const float lz = cb[lastIdx * 3 + 2];
#pragma unroll
        for (int k = 0; k < 8; k++) {
            float dx = px[k] - lx, dy = py[k] - ly, dz = pz[k] - lz;
            float d2 = dx * dx + dy * dy + dz * dz;   // contract off: numpy op order
            // conservative filter: if sqrt(d2) could beat dist, take the slow path.
            // margin (1+2e-6) > (1+ulp)^3 guarantees no false negatives.
            if (__any(d2 < d2ub[k])) {
                float d = sqrtf(d2);                  // correctly rounded = np.sqrt
                float nd = fminf(dist[k], d);
                dist[k] = nd;
                d2ub[k] = nd * nd * 1.000002f;
            }
        }
        // per-thread argmax (ascending k = ascending global idx -> first-max)
        float bd = dist[0]; int bk = 0;
#pragma unroll
        for (int k = 1; k < 8; k++) if (dist[k] > bd) { bd = dist[k]; bk = k; }
        int bi = t + bk * 1024;
        // wave argmax, first-index tie-break
#pragma unroll
        for (int off = 32; off >= 1; off >>= 1) {
            float odv = __shfl_down(bd, off, 64);
            int   oiv = __shfl_down(bi, off, 64);
            if (odv > bd || (odv == bd && oiv < bi)) { bd = odv; bi = oiv; }
        }
        if (lane == 0) { red_d[i & 1][wid] = bd; red_i[i & 1][wid] = bi; }
        __syncthreads();   // single barrier per iteration (parity double-buffer)
        float fbd = red_d[i & 1][0]; int fbi = red_i[i & 1][0];
#pragma unroll
        for (int w = 1; w < 16; w++) {
            float odv = red_d[i & 1][w]; int oiv = red_i[i & 1][w];
            if (odv > fbd || (odv == fbd && oiv < fbi)) { fbd = odv; fbi = oiv; }
        }
        lastIdx = fbi;
        // zero the picked point WITHOUT dynamic register indexing
#pragma unroll
        for (int k = 0; k < 8; k++)
            if (fbi == t + k * 1024) { dist[k] = 0.0f; d2ub[k] = 0.0f; }
        if (t == 0) {
            og[i] = fbi;
            if (i < 128) oc[i] = fbi;
            if (i < 64)  od[i] = fbi;
        }
    }
}

// ---------------- z stats + safety for global & component ----------------
__global__ __launch_bounds__(1024) void safety_gc_kernel(const float* __restrict__ coords,
                                                         const int* __restrict__ idx_all,
                                                         float* __restrict__ safety_all) {
    const int b = blockIdx.x;
    const int t = threadIdx.x;
    const float* cb = coords + (size_t)b * N_PTS * 3;
    float s1 = 0.f, s2 = 0.f;
#pragma unroll
    for (int k = 0; k < 8; k++) {
        float z = cb[(t + k * 1024) * 3 + 2];
        s1 += z; s2 += z * z;
    }
    __shared__ float r1[16], r2[16];
#pragma unroll
    for (int off = 32; off >= 1; off >>= 1) {
        s1 += __shfl_down(s1, off, 64);
        s2 += __shfl_down(s2, off, 64);
    }
    int lane = t & 63, wid = t >> 6;
    if (lane == 0) { r1[wid] = s1; r2[wid] = s2; }
    __syncthreads();
    float S1 = 0.f, S2 = 0.f;
#pragma unroll
    for (int w = 0; w < 16; w++) { S1 += r1[w]; S2 += r2[w]; }
    float mean = S1 / 8192.0f;
    float var1 = (S2 - S1 * S1 / 8192.0f) / 8191.0f;           // ddof=1
    float sc = 1.0f + expf(-var1 / 0.1f) * 0.9f;               // component safety
    for (int u = t; u < 256; u += 1024) {
        int p = idx_all[b * 256 + u];
        float z = cb[p * 3 + 2];
        float s = 1.0f + (1.0f / (1.0f + expf(-((z - mean) / 5.0f)))) * 0.95f;
        safety_all[b * 256 + u] = s;
    }
    for (int u = t; u < 128; u += 1024) safety_all[512 + b * 128 + u] = sc;
}

// ---------------- detail density safety: one block per sampled center ----------------
__global__ __launch_bounds__(256) void density_kernel(const float* __restrict__ coords,
                                                      const int* __restrict__ idx_all,
                                                      float* __restrict__ safety_all) {
#pragma clang fp contract(off)
    const int ci = blockIdx.x & 63;
    const int b  = blockIdx.x >> 6;
    const int t  = threadIdx.x;
    const float* cb = coords + (size_t)b * N_PTS * 3;
    const int p = idx_all[768 + b * 64 + ci];
    const float cx = cb[p * 3], cy = cb[p * 3 + 1], cz = cb[p * 3 + 2];
    const float cc = cx * cx + cy * cy + cz * cz;
    int cnt = 0;
    for (int k = 0; k < 32; k++) {
        int q = t + k * 256;
        float x = cb[q * 3], y = cb[q * 3 + 1], z = cb[q * 3 + 2];
        float pp = x * x + y * y + z * z;
        float dot = cx * x + cy * y + cz * z;
        float d2 = (cc + pp) - 2.0f * dot;   // same formula/order as reference _sqdist
        if (d2 < 0.25f) cnt++;
    }
#pragma unroll
    for (int off = 32; off >= 1; off >>= 1) cnt += __shfl_down(cnt, off, 64);
    __shared__ int rc[4];
    int lane = t & 63, wid = t >> 6;
    if (lane == 0) rc[wid] = cnt;
    __syncthreads();
    if (t == 0) {
        int tot = rc[0] + rc[1] + rc[2] + rc[3];
        safety_all[768 + b * 64 + ci] = 1.0f + ((float)tot / 8192.0f) * 0.95f;
    }
}

// ---------------- per-scale score MLP: 8 centers per block ----------------
__global__ __launch_bounds__(256) void score_kernel(
    const float* __restrict__ feat,
    const float* __restrict__ gW1, const float* __restrict__ gb1,
    const float* __restrict__ gW2, const float* __restrict__ gb2,
    const float* __restrict__ cW1, const float* __restrict__ cb1,
    const float* __restrict__ cW2, const float* __restrict__ cb2,
    const float* __restrict__ dW1, const float* __restrict__ db1,
    const float* __restrict__ dW2, const float* __restrict__ db2,
    const int* __restrict__ idx_all, const float* __restrict__ safety_all,
    float* __restrict__ final_all) {
    int bid = blockIdx.x;
    int b, c0, C, S, off;
    const float *W1, *b1, *W2, *b2;
    if (bid < 64)      { C = 256; S = 16; W1 = gW1; b1 = gb1; W2 = gW2; b2 = gb2; b = bid >> 5; c0 = (bid & 31) * 8; off = 0; }
    else if (bid < 96) { int r = bid - 64; C = 128; S = 16; W1 = cW1; b1 = cb1; W2 = cW2; b2 = cb2; b = r >> 4; c0 = (r & 15) * 8; off = 512; }
    else               { int r = bid - 96; C = 64;  S = 8;  W1 = dW1; b1 = db1; W2 = dW2; b2 = db2; b = r >> 3; c0 = (r & 7) * 8; off = 768; }

    __shared__ float xt[8 * 772];
    __shared__ float h1s[8 * 260];
    __shared__ float ps[8 * 16];
    __shared__ int pid[8];
    const int t = threadIdx.x;
    if (t < 8) pid[t] = idx_all[off + b * C + c0 + t];
    __syncthreads();

    for (int r = 0; r < 8; r++) {
        const float* src = feat + ((size_t)b * N_PTS + pid[r]) * D_FEAT;
        for (int c = t; c < 768; c += 256) xt[r * 772 + c] = src[c];
    }
    __syncthreads();

    {
        int rp = t & 3;
        int jg = t >> 2;
        int r0 = rp * 2;
        if (jg * 4 < C) {
            float4 acc0[4], acc1[4];
#pragma unroll
            for (int a = 0; a < 4; a++) { acc0[a] = make_float4(0, 0, 0, 0); acc1[a] = make_float4(0, 0, 0, 0); }
            for (int k = 0; k < 768; k += 4) {
                float4 x0 = *(const float4*)&xt[r0 * 772 + k];
                float4 x1 = *(const float4*)&xt[(r0 + 1) * 772 + k];
#pragma unroll
                for (int a = 0; a < 4; a++) {
                    int j = jg * 4 + a;
                    float4 w = *(const float4*)&W1[(size_t)j * 768 + k];
                    acc0[a].x = fmaf(w.x, x0.x, acc0[a].x); acc0[a].y = fmaf(w.y, x0.y, acc0[a].y);
                    acc0[a].z = fmaf(w.z, x0.z, acc0[a].z); acc0[a].w = fmaf(w.w, x0.w, acc0[a].w);
                    acc1[a].x = fmaf(w.x, x1.x, acc1[a].x); acc1[a].y = fmaf(w.y, x1.y, acc1[a].y);
                    acc1[a].z = fmaf(w.z, x1.z, acc1[a].z); acc1[a].w = fmaf(w.w, x1.w, acc1[a].w);
                }
            }
#pragma unroll
            for (int a = 0; a < 4; a++) {
                int j = jg * 4 + a;
                float bb = b1[j];
                float v0 = (acc0[a].x + acc0[a].y) + (acc0[a].z + acc0[a].w) + bb;
                float v1 = (acc1[a].x + acc1[a].y) + (acc1[a].z + acc1[a].w) + bb;
                h1s[r0 * 260 + j]       = fmaxf(v0, 0.f);
                h1s[(r0 + 1) * 260 + j] = fmaxf(v1, 0.f);
            }
        }
    }
    __syncthreads();

    if (t < 8 * S) {
        int r = t / S, s = t % S;
        float4 a = make_float4(0, 0, 0, 0);
        for (int k = 0; k < C; k += 4) {
            float4 w = *(const float4*)&W2[s * C + k];
            float4 h = *(const float4*)&h1s[r * 260 + k];
            a.x = fmaf(w.x, h.x, a.x); a.y = fmaf(w.y, h.y, a.y);
            a.z = fmaf(w.z, h.z, a.z); a.w = fmaf(w.w, h.w, a.w);
        }
        float logit = (a.x + a.y) + (a.z + a.w) + b2[s];
        ps[r * 16 + s] = 1.0f / (1.0f + expf(-logit));
    }
    __syncthreads();
    if (t < 8) {
        float m = 0.f;
        for (int s = 0; s < S; s++) m += ps[t * 16 + s];
        m /= (float)S;
        final_all[off + b * C + c0 + t] = m * safety_all[off + b * C + c0 + t];
    }
}

// ---------------- top-k per (scale,batch): single wave ----------------
__global__ __launch_bounds__(64) void topk_kernel(const int* __restrict__ idx_all,
                                                  const float* __restrict__ final_all,
                                                  int* __restrict__ tok_pidx) {
    int bid = blockIdx.x;  // 0..5
    int scale = bid >> 1, b = bid & 1;
    int C = (scale == 0) ? 256 : (scale == 1) ? 128 : 64;
    int S = (scale == 2) ? 8 : 16;
    int off = (scale == 0) ? 0 : (scale == 1) ? 512 : 768;
    int base = (scale == 0) ? 0 : (scale == 1) ? 16 : 32;
    int lane = threadIdx.x;
    float v[4];
#pragma unroll
    for (int j = 0; j < 4; j++) {
        int i = lane + j * 64;
        v[j] = (i < C) ? final_all[off + b * C + i] : -INFINITY;
    }
    for (int s = 0; s < S; s++) {
        float bd = -INFINITY; int bi = 0x7fffffff;
#pragma unroll
        for (int j = 0; j < 4; j++) {
            int i = lane + j * 64;
            if (i < C && v[j] > bd) { bd = v[j]; bi = i; }
        }
        for (int m = 1; m < 64; m <<= 1) {
            float odv = __shfl_xor(bd, m, 64);
            int   oiv = __shfl_xor(bi, m, 64);
            if (odv > bd || (odv == bd && oiv < bi)) { bd = odv; bi = oiv; }
        }
        // no dynamic register indexing: unrolled conditional clear
#pragma unroll
        for (int j = 0; j < 4; j++)
            if ((bi >> 6) == j && lane == (bi & 63)) v[j] = -INFINITY;
        if (lane == 0) tok_pidx[b * 40 + base + s] = idx_all[off + b * C + bi];
    }
}

// ---------------- final MLP + LayerNorm: 2 tokens per block ----------------
__global__ __launch_bounds__(256) void final_kernel(
    const float* __restrict__ feat, const int* __restrict__ tok_pidx,
    const float* __restrict__ pW1, const float* __restrict__ pb1,
    const float* __restrict__ pW2, const float* __restrict__ pb2,
    const float* __restrict__ lng, const float* __restrict__ lnb,
    float* __restrict__ out) {
    int bid = blockIdx.x;               // 40 blocks
    int b = bid / 20, pr = bid % 20;
    int t = threadIdx.x;
    __shared__ float xt[2 * 772];
    __shared__ float h1s[2 * 388];
    __shared__ float red[16];

    for (int r = 0; r < 2; r++) {
        int tok = pr * 2 + r;
        int p = tok_pidx[b * 40 + tok];
        const float* src = feat + ((size_t)b * N_PTS + p) * D_FEAT;
        for (int c = t; c < 768; c += 256) xt[r * 772 + c] = src[c];
    }
    __syncthreads();

    for (int u = t; u < 768; u += 256) {
        int j = u >> 1, r = u & 1;
        float4 a = make_float4(0, 0, 0, 0);
        for (int k = 0; k < 768; k += 4) {
            float4 w = *(const float4*)&pW1[(size_t)j * 768 + k];
            float4 x = *(const float4*)&xt[r * 772 + k];
            a.x = fmaf(w.x, x.x, a.x); a.y = fmaf(w.y, x.y, a.y);
            a.z = fmaf(w.z, x.z, a.z); a.w = fmaf(w.w, x.w, a.w);
        }
        float v = (a.x + a.y) + (a.z + a.w) + pb1[j];
        h1s[r * 388 + j] = fmaxf(v, 0.f);
    }
    __syncthreads();

    for (int u = t; u < 1536; u += 256) {
        int o = u >> 1, r = u & 1;
        float4 a = make_float4(0, 0, 0, 0);
        for (int k = 0; k < 384; k += 4) {
            float4 w = *(const float4*)&pW2[(size_t)o * 384 + k];
            float4 h = *(const float4*)&h1s[r * 388 + k];
            a.x = fmaf(w.x, h.x, a.x); a.y = fmaf(w.y, h.y, a.y);
            a.z = fmaf(w.z, h.z, a.z); a.w = fmaf(w.w, h.w, a.w);
        }
        xt[r * 772 + o] = (a.x + a.y) + (a.z + a.w) + pb2[o];
    }
    __syncthreads();

    for (int r = 0; r < 2; r++) {
        float s1 = 0.f, s2 = 0.f;
        for (int o = t; o < 768; o += 256) { float v = xt[r * 772 + o]; s1 += v; s2 += v * v; }
#pragma unroll
        for (int off2 = 32; off2 >= 1; off2 >>= 1) {
            s1 += __shfl_down(s1, off2, 64);
            s2 += __shfl_down(s2, off2, 64);
        }
        int lane = t & 63, wid = t >> 6;
        if (lane == 0) { red[wid * 2] = s1; red[wid * 2 + 1] = s2; }
        __syncthreads();
        float S1 = red[0] + red[2] + red[4] + red[6];
        float S2 = red[1] + red[3] + red[5] + red[7];
        float mu = S1 / 768.0f;
        float var = S2 / 768.0f - mu * mu;
        float inv = rsqrtf(var + 1e-5f);
        int tok = pr * 2 + r;
        float* dst = out + ((size_t)b * 40 + tok) * 768;
        for (int o = t; o < 768; o += 256) {
            float v = xt[r * 772 + o];
            dst[o] = (v - mu) * inv * lng[o] + lnb[o];
        }
        __syncthreads();
    }
}

extern "C" void kernel_launch(void* const* d_in, const int* in_sizes, int n_in,
                              void* d_out, int out_size, void* d_ws, size_t ws_size,
                              hipStream_t stream) {
    const float* feat   = (const float*)d_in[0];
    const float* coords = (const float*)d_in[1];
    const float* gW1 = (const float*)d_in[2],  *gb1 = (const float*)d_in[3];
    const float* gW2 = (const float*)d_in[4],  *gb2 = (const float*)d_in[5];
    const float* cW1 = (const float*)d_in[6],  *cb1 = (const float*)d_in[7];
    const float* cW2 = (const float*)d_in[8],  *cb2 = (const float*)d_in[9];
    const float* dW1 = (const float*)d_in[10], *db1 = (const float*)d_in[11];
    const float* dW2 = (const float*)d_in[12], *db2 = (const float*)d_in[13];
    const float* pW1 = (const float*)d_in[14], *pb1 = (const float*)d_in[15];
    const float* pW2 = (const float*)d_in[16], *pb2 = (const float*)d_in[17];
    const float* lng = (const float*)d_in[18], *lnb = (const float*)d_in[19];
    float* out = (float*)d_out;

    int*   idx_all    = (int*)d_ws;
    float* safety_all = (float*)d_ws + 896;
    float* final_all  = (float*)d_ws + 1792;
    int*   tok_pidx   = (int*)d_ws + 2688;

    fps_kernel<<<2, 1024, 0, stream>>>(coords, idx_all);
    safety_gc_kernel<<<2, 1024, 0, stream>>>(coords, idx_all, safety_all);
    density_kernel<<<128, 256, 0, stream>>>(coords, idx_all, safety_all);
    score_kernel<<<112, 256, 0, stream>>>(feat, gW1, gb1, gW2, gb2, cW1, cb1, cW2, cb2,
                                          dW1, db1, dW2, db2, idx_all, safety_all, final_all);
    topk_kernel<<<6, 64, 0, stream>>>(idx_all, final_all, tok_pidx);
    final_kernel<<<40, 256, 0, stream>>>(feat, tok_pidx, pW1, pb1, pW2, pb2, lng, lnb, out);
}